// Round 1
// baseline (15988.052 us; speedup 1.0000x reference)
//
#include <hip/hip_runtime.h>

typedef unsigned short u16;
typedef unsigned int u32;
typedef float f32x4 __attribute__((ext_vector_type(4)));
typedef __bf16 bf16x8 __attribute__((ext_vector_type(8)));
typedef u16 u16x8 __attribute__((ext_vector_type(8)));

#define T_STEPS 512
#define BATCH 64
#define HDIM 1024
#define GDIM 4096            // 4*H
#define HS_ELEMS (33554432u) // 512*64*1024
#define NBLK 256

__device__ __forceinline__ u16 f2bf(float f) {
  union { float f; u32 u; } v; v.f = f;
  u32 r = v.u + 0x7fffu + ((v.u >> 16) & 1u);
  return (u16)(r >> 16);
}
__device__ __forceinline__ float bf2f(u16 b) {
  union { u32 u; float f; } v; v.u = ((u32)b) << 16;
  return v.f;
}
__device__ __forceinline__ float sigm(float x) { return 1.f / (1.f + __expf(-x)); }
__device__ __forceinline__ float tanh_fast(float x) { return 1.f - 2.f / (__expf(2.f * x) + 1.f); }

// ---------------------------------------------------------------------------
// Kernel 1: transpose+convert W_x, W_h: [1024][4096] fp32 -> [4096][1024] bf16.
// Block (0,0,0) also zeroes the grid-barrier flag array (4096 ints).
// ---------------------------------------------------------------------------
__global__ void transpose_w(const float* __restrict__ Wx, const float* __restrict__ Wh,
                            u16* __restrict__ WxT, u16* __restrict__ WhT,
                            int* __restrict__ flags) {
  if (blockIdx.x == 0 && blockIdx.y == 0 && blockIdx.z == 0) {
    int tt = threadIdx.y * 32 + threadIdx.x;
    for (int i = tt; i < 4096; i += 256) flags[i] = 0;
  }
  __shared__ float tile[32][33];
  const float* src = blockIdx.z ? Wh : Wx;
  u16* dst = blockIdx.z ? WhT : WxT;
  const int n0 = blockIdx.x * 32, k0 = blockIdx.y * 32;
  const int tx = threadIdx.x, ty = threadIdx.y;
#pragma unroll
  for (int i = 0; i < 4; ++i)
    tile[ty + i * 8][tx] = src[(size_t)(k0 + ty + i * 8) * GDIM + n0 + tx];
  __syncthreads();
#pragma unroll
  for (int i = 0; i < 4; ++i)
    dst[(size_t)(n0 + ty + i * 8) * HDIM + k0 + tx] = f2bf(tile[tx][ty + i * 8]);
}

// ---------------------------------------------------------------------------
// Kernel 2: Xp[m][n] = bf16( X[m][:] @ W_x[:][n] + b[n] ),  M=32768, N=4096, K=1024
// 128x128 tile, 4 waves (each 64x64 = 4x4 frags of 16x16), BK=32, reg-staged LDS,
// fused fp32->bf16 conversion of X during staging. B operand = pre-transposed WxT.
// ---------------------------------------------------------------------------
__global__ __launch_bounds__(256, 2) void gemm_xp(
    const float* __restrict__ X, const u16* __restrict__ WxT,
    const float* __restrict__ bias, u16* __restrict__ Xp) {
  __shared__ u16 As[128 * 40]; // row stride 40 (pad) to spread banks
  __shared__ u16 Bs[128 * 40];
  const int tid = threadIdx.x;
  const int lane = tid & 63, w = tid >> 6;
  const int rl = lane & 15, gq = lane >> 4, g8 = gq * 8;
  // XCD-aware swizzle (8192 % 8 == 0 -> bijective), then m-major/n-minor
  const int swz = (blockIdx.x & 7) * 1024 + (blockIdx.x >> 3);
  const int m0 = (swz >> 5) * 128, n0 = (swz & 31) * 128;
  const int srow = tid >> 1, sseg = (tid & 1) * 16;
  const int rbase = (w >> 1) * 64, cbase = (w & 1) * 64;

  f32x4 acc[4][4] = {};
  for (int k0 = 0; k0 < 1024; k0 += 32) {
    const float4* ap = (const float4*)&X[(size_t)(m0 + srow) * 1024 + k0 + sseg];
    float4 v0 = ap[0], v1 = ap[1], v2 = ap[2], v3 = ap[3];
    u16x8 pa, pb;
    pa[0] = f2bf(v0.x); pa[1] = f2bf(v0.y); pa[2] = f2bf(v0.z); pa[3] = f2bf(v0.w);
    pa[4] = f2bf(v1.x); pa[5] = f2bf(v1.y); pa[6] = f2bf(v1.z); pa[7] = f2bf(v1.w);
    pb[0] = f2bf(v2.x); pb[1] = f2bf(v2.y); pb[2] = f2bf(v2.z); pb[3] = f2bf(v2.w);
    pb[4] = f2bf(v3.x); pb[5] = f2bf(v3.y); pb[6] = f2bf(v3.z); pb[7] = f2bf(v3.w);
    const u16x8* bp = (const u16x8*)&WxT[(size_t)(n0 + srow) * 1024 + k0 + sseg];
    u16x8 qa = bp[0], qb = bp[1];
    *(u16x8*)&As[srow * 40 + sseg] = pa;
    *(u16x8*)&As[srow * 40 + sseg + 8] = pb;
    *(u16x8*)&Bs[srow * 40 + sseg] = qa;
    *(u16x8*)&Bs[srow * 40 + sseg + 8] = qb;
    __syncthreads();
    bf16x8 av[4], bv[4];
#pragma unroll
    for (int i = 0; i < 4; ++i)
      av[i] = *(const bf16x8*)&As[(rbase + i * 16 + rl) * 40 + g8];
#pragma unroll
    for (int j = 0; j < 4; ++j)
      bv[j] = *(const bf16x8*)&Bs[(cbase + j * 16 + rl) * 40 + g8];
#pragma unroll
    for (int i = 0; i < 4; ++i)
#pragma unroll
      for (int j = 0; j < 4; ++j)
        acc[i][j] = __builtin_amdgcn_mfma_f32_16x16x32_bf16(av[i], bv[j], acc[i][j], 0, 0, 0);
    __syncthreads();
  }
#pragma unroll
  for (int j = 0; j < 4; ++j) {
    const int n = n0 + cbase + j * 16 + rl;
    const float bj = bias[n];
#pragma unroll
    for (int i = 0; i < 4; ++i)
#pragma unroll
      for (int r = 0; r < 4; ++r) {
        const int m = m0 + rbase + i * 16 + gq * 4 + r;
        Xp[(size_t)m * GDIM + n] = f2bf(acc[i][j][r] + bj);
      }
  }
}

// ---------------------------------------------------------------------------
// Grid barrier: per-block flag store (release) + every thread polls one flag.
// flags are padded to 64B (16 ints) per block to avoid line contention.
// Monotonic targets -> no reset needed within a launch.
// ---------------------------------------------------------------------------
__device__ __forceinline__ void grid_barrier(int* flags, int tgt) {
  __syncthreads(); // all block stores issued (vmcnt drained)
  if (threadIdx.x == 0) {
    __threadfence(); // release: write back this XCD's L2
    __hip_atomic_store(&flags[blockIdx.x * 16], tgt, __ATOMIC_RELAXED, __HIP_MEMORY_SCOPE_AGENT);
  }
  const int slot = threadIdx.x * 16;
  for (;;) {
    int v = __hip_atomic_load(&flags[slot], __ATOMIC_RELAXED, __HIP_MEMORY_SCOPE_AGENT);
    if (__syncthreads_count(v < tgt) == 0) break;
  }
  __threadfence(); // acquire: invalidate stale cached h
}

// ---------------------------------------------------------------------------
// Kernel 3: the recurrence. 256 blocks x 256 threads (4 waves).
// Block `cu` owns h-columns [cu*4, cu*4+4) -> 16 gate columns {i,f,g,o}x4.
// W_h slice lives in LDS ([col][k], padded) for all 512 steps; c in registers.
// h ping-pongs through global bf16 buffer (2 x 64 x 1024).
// Per step: wave w computes gates for batches [w*16, w*16+16) via 32 MFMAs,
// gate exchange through LDS, fused elementwise, custom grid barrier.
// ---------------------------------------------------------------------------
__global__ __launch_bounds__(256, 1) void lstm_rec(
    const u16* __restrict__ Xp, const u16* __restrict__ WhT,
    u16* __restrict__ h_buf, int* __restrict__ flags, float* __restrict__ out) {
  __shared__ u16 W_lds[16 * 1032]; // [16 cols][1024 k], row pad 8
  __shared__ float gate_lds[64][16];
  const int cu = blockIdx.x;
  const int tid = threadIdx.x;
  const int lane = tid & 63, w = tid >> 6;
  const int rl = lane & 15, gq = lane >> 4, g8 = gq * 8;

  // stage W_h slice: col c -> global gate column (c>>2)*1024 + cu*4 + (c&3)
  for (int u = tid; u < 2048; u += 256) {
    const int c = u >> 7, p = u & 127;
    const int gcol = (c >> 2) * 1024 + cu * 4 + (c & 3);
    *(u16x8*)&W_lds[c * 1032 + p * 8] = *(const u16x8*)&WhT[(size_t)gcol * HDIM + p * 8];
  }
  // zero h_buf[0] (this block's 256-element slice)
  h_buf[cu * 256 + tid] = 0;
  grid_barrier(flags, 1);

  const int b_el = tid >> 2, jj = tid & 3;
  float creg = 0.f, hreg = 0.f;
  const u16* hrow_base = nullptr;

  for (int t = 0; t < T_STEPS; ++t) {
    const u16* hc = h_buf + (t & 1) * (BATCH * HDIM);
    u16* hn = h_buf + ((t & 1) ^ 1) * (BATCH * HDIM);

    // prefetch Xp for the elementwise phase (hidden under the MFMA loop)
    const size_t xb = ((size_t)t * BATCH + b_el) * GDIM + cu * 4 + jj;
    const u16 px0 = Xp[xb];
    const u16 px1 = Xp[xb + 1024];
    const u16 px2 = Xp[xb + 2048];
    const u16 px3 = Xp[xb + 3072];

    f32x4 acc = {0.f, 0.f, 0.f, 0.f};
    const u16* hrow = &hc[(w * 16 + rl) * HDIM + g8];
    const u16* wrow = &W_lds[rl * 1032 + g8];
#pragma unroll
    for (int kk = 0; kk < 32; ++kk) {
      bf16x8 a = *(const bf16x8*)(hrow + kk * 32);
      bf16x8 bb = *(const bf16x8*)(wrow + kk * 32);
      acc = __builtin_amdgcn_mfma_f32_16x16x32_bf16(a, bb, acc, 0, 0, 0);
    }
#pragma unroll
    for (int q = 0; q < 4; ++q)
      gate_lds[w * 16 + gq * 4 + q][rl] = acc[q];
    __syncthreads();
    {
      const float g0 = gate_lds[b_el][jj] + bf2f(px0);
      const float g1 = gate_lds[b_el][4 + jj] + bf2f(px1);
      const float g2 = gate_lds[b_el][8 + jj] + bf2f(px2);
      const float g3 = gate_lds[b_el][12 + jj] + bf2f(px3);
      const float iv = sigm(g0);
      const float fv = sigm(g1);
      const float gv = tanh_fast(g2);
      const float ov = sigm(g3);
      creg = fv * creg + iv * gv;
      hreg = ov * tanh_fast(creg);
      out[((size_t)t * BATCH + b_el) * HDIM + cu * 4 + jj] = hreg;
      hn[b_el * HDIM + cu * 4 + jj] = f2bf(hreg);
    }
    grid_barrier(flags, t + 2);
  }
  // hT, cT
  out[(size_t)HS_ELEMS + (size_t)b_el * HDIM + cu * 4 + jj] = hreg;
  out[(size_t)HS_ELEMS + 65536u + (size_t)b_el * HDIM + cu * 4 + jj] = creg;
  (void)hrow_base;
}

// ---------------------------------------------------------------------------
// Workspace layout (bytes):
//   [0,        16384)    barrier flags (256 blocks x 16 ints)
//   [65536,    327680)   h ping-pong: 2 x 64 x 1024 bf16 = 262144
//   [327680,   +8MB)     WxT  [4096][1024] bf16
//   [+8MB,     +16MB)    WhT  [4096][1024] bf16
//   [17104896, +256MB)   Xp   [32768][4096] bf16
// total ~272.3 MB
// ---------------------------------------------------------------------------
extern "C" void kernel_launch(void* const* d_in, const int* in_sizes, int n_in,
                              void* d_out, int out_size, void* d_ws, size_t ws_size,
                              hipStream_t stream) {
  const float* x = (const float*)d_in[0];
  const float* Wx = (const float*)d_in[1];
  const float* Wh = (const float*)d_in[2];
  const float* bias = (const float*)d_in[3];
  float* out = (float*)d_out;
  char* ws = (char*)d_ws;

  int* flags = (int*)(ws + 0);
  u16* h_buf = (u16*)(ws + 65536);
  u16* WxT = (u16*)(ws + 327680);
  u16* WhT = (u16*)(ws + 327680 + 8388608);
  u16* Xp = (u16*)(ws + 327680 + 16777216);

  transpose_w<<<dim3(128, 32, 2), dim3(32, 8), 0, stream>>>(Wx, Wh, WxT, WhT, flags);
  gemm_xp<<<dim3(8192), dim3(256), 0, stream>>>(x, WxT, bias, Xp);
  lstm_rec<<<dim3(256), dim3(256), 0, stream>>>(Xp, WhT, h_buf, flags, out);
}

// Round 2
// 5639.528 us; speedup vs baseline: 2.8350x; 2.8350x over previous
//
#include <hip/hip_runtime.h>

typedef unsigned short u16;
typedef unsigned int u32;
typedef unsigned long long u64;
typedef float f32x4 __attribute__((ext_vector_type(4)));
typedef __bf16 bf16x8 __attribute__((ext_vector_type(8)));
typedef u16 u16x8 __attribute__((ext_vector_type(8)));

#define T_STEPS 512
#define BATCH 64
#define HDIM 1024
#define GDIM 4096            // 4*H
#define HS_ELEMS (33554432u) // 512*64*1024

__device__ __forceinline__ u16 f2bf(float f) {
  union { float f; u32 u; } v; v.f = f;
  u32 r = v.u + 0x7fffu + ((v.u >> 16) & 1u);
  return (u16)(r >> 16);
}
__device__ __forceinline__ float bf2f(u16 b) {
  union { u32 u; float f; } v; v.u = ((u32)b) << 16;
  return v.f;
}
__device__ __forceinline__ float sigm(float x) { return 1.f / (1.f + __expf(-x)); }
__device__ __forceinline__ float tanh_fast(float x) { return 1.f - 2.f / (__expf(2.f * x) + 1.f); }

// ---------------------------------------------------------------------------
// Kernel 1: transpose+convert W_x, W_h: [1024][4096] fp32 -> [4096][1024] bf16.
// Block (0,0,0) also zeroes the grid-barrier flag array (replay safety: the
// harness does NOT re-poison ws between graph replays; flags are re-zeroed
// at the start of every launch, before lstm_rec runs, via stream ordering).
// ---------------------------------------------------------------------------
__global__ void transpose_w(const float* __restrict__ Wx, const float* __restrict__ Wh,
                            u16* __restrict__ WxT, u16* __restrict__ WhT,
                            int* __restrict__ flags) {
  if (blockIdx.x == 0 && blockIdx.y == 0 && blockIdx.z == 0) {
    int tt = threadIdx.y * 32 + threadIdx.x;
    for (int i = tt; i < 4096; i += 256) flags[i] = 0;
  }
  __shared__ float tile[32][33];
  const float* src = blockIdx.z ? Wh : Wx;
  u16* dst = blockIdx.z ? WhT : WxT;
  const int n0 = blockIdx.x * 32, k0 = blockIdx.y * 32;
  const int tx = threadIdx.x, ty = threadIdx.y;
#pragma unroll
  for (int i = 0; i < 4; ++i)
    tile[ty + i * 8][tx] = src[(size_t)(k0 + ty + i * 8) * GDIM + n0 + tx];
  __syncthreads();
#pragma unroll
  for (int i = 0; i < 4; ++i)
    dst[(size_t)(n0 + ty + i * 8) * HDIM + k0 + tx] = f2bf(tile[tx][ty + i * 8]);
}

// ---------------------------------------------------------------------------
// Kernel 2: Xp[m][n] = bf16( X[m][:] @ W_x[:][n] + b[n] ),  M=32768, N=4096, K=1024
// (unchanged from R1: ~600us, not the bottleneck this round)
// ---------------------------------------------------------------------------
__global__ __launch_bounds__(256, 2) void gemm_xp(
    const float* __restrict__ X, const u16* __restrict__ WxT,
    const float* __restrict__ bias, u16* __restrict__ Xp) {
  __shared__ u16 As[128 * 40];
  __shared__ u16 Bs[128 * 40];
  const int tid = threadIdx.x;
  const int lane = tid & 63, w = tid >> 6;
  const int rl = lane & 15, gq = lane >> 4, g8 = gq * 8;
  const int swz = (blockIdx.x & 7) * 1024 + (blockIdx.x >> 3);
  const int m0 = (swz >> 5) * 128, n0 = (swz & 31) * 128;
  const int srow = tid >> 1, sseg = (tid & 1) * 16;
  const int rbase = (w >> 1) * 64, cbase = (w & 1) * 64;

  f32x4 acc[4][4] = {};
  for (int k0 = 0; k0 < 1024; k0 += 32) {
    const float4* ap = (const float4*)&X[(size_t)(m0 + srow) * 1024 + k0 + sseg];
    float4 v0 = ap[0], v1 = ap[1], v2 = ap[2], v3 = ap[3];
    u16x8 pa, pb;
    pa[0] = f2bf(v0.x); pa[1] = f2bf(v0.y); pa[2] = f2bf(v0.z); pa[3] = f2bf(v0.w);
    pa[4] = f2bf(v1.x); pa[5] = f2bf(v1.y); pa[6] = f2bf(v1.z); pa[7] = f2bf(v1.w);
    pb[0] = f2bf(v2.x); pb[1] = f2bf(v2.y); pb[2] = f2bf(v2.z); pb[3] = f2bf(v2.w);
    pb[4] = f2bf(v3.x); pb[5] = f2bf(v3.y); pb[6] = f2bf(v3.z); pb[7] = f2bf(v3.w);
    const u16x8* bp = (const u16x8*)&WxT[(size_t)(n0 + srow) * 1024 + k0 + sseg];
    u16x8 qa = bp[0], qb = bp[1];
    *(u16x8*)&As[srow * 40 + sseg] = pa;
    *(u16x8*)&As[srow * 40 + sseg + 8] = pb;
    *(u16x8*)&Bs[srow * 40 + sseg] = qa;
    *(u16x8*)&Bs[srow * 40 + sseg + 8] = qb;
    __syncthreads();
    bf16x8 av[4], bv[4];
#pragma unroll
    for (int i = 0; i < 4; ++i)
      av[i] = *(const bf16x8*)&As[(rbase + i * 16 + rl) * 40 + g8];
#pragma unroll
    for (int j = 0; j < 4; ++j)
      bv[j] = *(const bf16x8*)&Bs[(cbase + j * 16 + rl) * 40 + g8];
#pragma unroll
    for (int i = 0; i < 4; ++i)
#pragma unroll
      for (int j = 0; j < 4; ++j)
        acc[i][j] = __builtin_amdgcn_mfma_f32_16x16x32_bf16(av[i], bv[j], acc[i][j], 0, 0, 0);
    __syncthreads();
  }
#pragma unroll
  for (int j = 0; j < 4; ++j) {
    const int n = n0 + cbase + j * 16 + rl;
    const float bj = bias[n];
#pragma unroll
    for (int i = 0; i < 4; ++i)
#pragma unroll
      for (int r = 0; r < 4; ++r) {
        const int m = m0 + rbase + i * 16 + gq * 4 + r;
        Xp[(size_t)m * GDIM + n] = f2bf(acc[i][j][r] + bj);
      }
  }
}

// ---------------------------------------------------------------------------
// Grid barrier v2: no threadfence (all shared data is agent-scope / cache-
// bypassing). Per-wave vmcnt drain + block barrier + one relaxed flag store;
// only wave 0 polls (contiguous flags, 16B/lane), one syncthreads to release.
// Targets are monotonic within a launch; flags re-zeroed each launch.
// ---------------------------------------------------------------------------
__device__ __forceinline__ void grid_barrier(int* flags, int tgt, int tid) {
  asm volatile("s_waitcnt vmcnt(0)" ::: "memory"); // this wave's h/out stores done
  __syncthreads();                                 // all waves drained
  if (tid == 0)
    __hip_atomic_store(&flags[blockIdx.x], tgt, __ATOMIC_RELAXED, __HIP_MEMORY_SCOPE_AGENT);
  if (tid < 64) {
    const u64* f8 = (const u64*)flags;
    for (;;) {
      u64 a = __hip_atomic_load(&f8[tid * 2], __ATOMIC_RELAXED, __HIP_MEMORY_SCOPE_AGENT);
      u64 b = __hip_atomic_load(&f8[tid * 2 + 1], __ATOMIC_RELAXED, __HIP_MEMORY_SCOPE_AGENT);
      int m = min(min((int)(u32)a, (int)(a >> 32)), min((int)(u32)b, (int)(b >> 32)));
      if (__all(m >= tgt)) break;
    }
  }
  __syncthreads();
}

// ---------------------------------------------------------------------------
// Kernel 3 v2: recurrence, batch x column partition.
// 256 blocks = 4 batch-groups (bg: 16 batches) x 64 col-groups (cg: 16 h-cols).
// Wave w computes gate type w (i,f,g,o) for the block's 16x16 tile.
// W_h fragments live in VGPRs (32 x bf16x8 per lane) for all 512 steps.
// Per step: stage own h slice (32KB) via agent loads -> XOR-swizzled LDS,
// 32 MFMAs (2 acc chains), gate exchange via 4KB LDS, fused elementwise,
// paired bf16 h stores at agent scope, grid barrier.
// ---------------------------------------------------------------------------
__global__ __launch_bounds__(256, 1) void lstm_rec(
    const u16* __restrict__ Xp, const u16* __restrict__ WhT,
    u16* __restrict__ h_buf, int* __restrict__ flags, float* __restrict__ out) {
  __shared__ u16 h_lds[16 * 1024]; // [16 rows][1024 k] bf16, XOR-swizzled
  __shared__ float gate_lds[4][16][16];
  const int tid = threadIdx.x;
  const int lane = tid & 63, w = tid >> 6;
  const int rl = lane & 15, gq = lane >> 4;
  const int cg = blockIdx.x & 63, bg = blockIdx.x >> 6;

  // --- W_h fragments -> VGPRs (held across all 512 steps) ---
  // wave w's B operand: gate cols {w*1024 + cg*16 + rl}, k-major from WhT.
  bf16x8 wf[32];
  {
    const size_t gcol = (size_t)(w * 1024 + cg * 16 + rl) * HDIM + gq * 8;
#pragma unroll
    for (int kk = 0; kk < 32; ++kk)
      wf[kk] = *(const bf16x8*)&WhT[gcol + kk * 32];
  }

  const int b_el = tid >> 4, hc = tid & 15; // elementwise ownership: 16x16 tile
  float creg = 0.f, hreg = 0.f;
  const int srow = tid >> 4, sseg = tid & 15; // staging roles

  for (int t = 0; t < T_STEPS; ++t) {
    const u16* h_cur = h_buf + (t & 1) * (BATCH * HDIM);
    u16* h_next = h_buf + ((t & 1) ^ 1) * (BATCH * HDIM);

    // Xp prefetch for the elementwise phase (plain cached loads; caches are
    // never invalidated in this scheme)
    const size_t xb = ((size_t)t * BATCH + bg * 16 + b_el) * GDIM + cg * 16 + hc;
    const u16 px0 = Xp[xb];
    const u16 px1 = Xp[xb + 1024];
    const u16 px2 = Xp[xb + 2048];
    const u16 px3 = Xp[xb + 3072];

    f32x4 acc0 = {0.f, 0.f, 0.f, 0.f}, acc1 = {0.f, 0.f, 0.f, 0.f};
    if (t > 0) {
      // stage h slice [bg*16 .. +16) x [0,1024) -> LDS, coherent 8B loads.
      // thread: row=srow, 16 loads of 4 bf16; coalesced 128B chunks per u.
      const size_t gbase = (size_t)(bg * 16 + srow) * HDIM;
      const int lbase = srow * 2048, swz = (srow & 7) << 4;
#pragma unroll
      for (int u = 0; u < 16; ++u) {
        u64 v = __hip_atomic_load((const u64*)&h_cur[gbase + u * 64 + sseg * 4],
                                  __ATOMIC_RELAXED, __HIP_MEMORY_SCOPE_AGENT);
        *(u64*)((char*)h_lds + lbase + (((u * 128 + sseg * 8)) ^ swz)) = v;
      }
      __syncthreads();
      // MFMA: gates_w[16b x 16hc] += h[16x1024] @ W_slice[1024x16]
      const int abase = rl * 2048, aswz = (rl & 7) << 4, g16 = gq * 16;
#pragma unroll
      for (int kk = 0; kk < 32; kk += 2) {
        bf16x8 a0 = *(const bf16x8*)((const char*)h_lds + abase + ((kk * 64 + g16) ^ aswz));
        bf16x8 a1 = *(const bf16x8*)((const char*)h_lds + abase + (((kk + 1) * 64 + g16) ^ aswz));
        acc0 = __builtin_amdgcn_mfma_f32_16x16x32_bf16(a0, wf[kk], acc0, 0, 0, 0);
        acc1 = __builtin_amdgcn_mfma_f32_16x16x32_bf16(a1, wf[kk + 1], acc1, 0, 0, 0);
      }
      acc0 += acc1;
    } else {
      __syncthreads();
    }
    // gate exchange: C layout row=gq*4+r, col=rl
#pragma unroll
    for (int r = 0; r < 4; ++r)
      gate_lds[w][gq * 4 + r][rl] = acc0[r];
    __syncthreads();
    // elementwise: thread owns (b_el, hc)
    {
      const float gi = gate_lds[0][b_el][hc] + bf2f(px0);
      const float gf = gate_lds[1][b_el][hc] + bf2f(px1);
      const float gg = gate_lds[2][b_el][hc] + bf2f(px2);
      const float go = gate_lds[3][b_el][hc] + bf2f(px3);
      const float iv = sigm(gi);
      const float fv = sigm(gf);
      const float gv = tanh_fast(gg);
      const float ov = sigm(go);
      creg = fv * creg + iv * gv;
      hreg = ov * tanh_fast(creg);
      out[((size_t)t * BATCH + bg * 16 + b_el) * HDIM + cg * 16 + hc] = hreg;
      // paired bf16 store (4B, agent scope, cache-bypass)
      const u16 hv = f2bf(hreg);
      const u32 nb = (u32)__shfl_xor((int)hv, 1);
      if ((tid & 1) == 0) {
        const u32 word = (u32)hv | (nb << 16);
        __hip_atomic_store((u32*)&h_next[(size_t)(bg * 16 + b_el) * HDIM + cg * 16 + hc],
                           word, __ATOMIC_RELAXED, __HIP_MEMORY_SCOPE_AGENT);
      }
    }
    grid_barrier(flags, t + 1, tid);
  }
  // hT, cT
  out[(size_t)HS_ELEMS + (size_t)(bg * 16 + b_el) * HDIM + cg * 16 + hc] = hreg;
  out[(size_t)HS_ELEMS + 65536u + (size_t)(bg * 16 + b_el) * HDIM + cg * 16 + hc] = creg;
}

// ---------------------------------------------------------------------------
// Workspace layout (bytes):
//   [0,        16384)    barrier flags (256 ints used, contiguous)
//   [65536,    327680)   h ping-pong: 2 x 64 x 1024 bf16 = 262144
//   [327680,   +8MB)     WxT  [4096][1024] bf16
//   [+8MB,     +16MB)    WhT  [4096][1024] bf16
//   [17104896, +256MB)   Xp   [32768][4096] bf16
// ---------------------------------------------------------------------------
extern "C" void kernel_launch(void* const* d_in, const int* in_sizes, int n_in,
                              void* d_out, int out_size, void* d_ws, size_t ws_size,
                              hipStream_t stream) {
  const float* x = (const float*)d_in[0];
  const float* Wx = (const float*)d_in[1];
  const float* Wh = (const float*)d_in[2];
  const float* bias = (const float*)d_in[3];
  float* out = (float*)d_out;
  char* ws = (char*)d_ws;

  int* flags = (int*)(ws + 0);
  u16* h_buf = (u16*)(ws + 65536);
  u16* WxT = (u16*)(ws + 327680);
  u16* WhT = (u16*)(ws + 327680 + 8388608);
  u16* Xp = (u16*)(ws + 327680 + 16777216);

  transpose_w<<<dim3(128, 32, 2), dim3(32, 8), 0, stream>>>(Wx, Wh, WxT, WhT, flags);
  gemm_xp<<<dim3(8192), dim3(256), 0, stream>>>(x, WxT, bias, Xp);
  lstm_rec<<<dim3(256), dim3(256), 0, stream>>>(Xp, WhT, h_buf, flags, out);
}